// Round 5
// baseline (136.869 us; speedup 1.0000x reference)
//
#include <hip/hip_runtime.h>
#include <math.h>

#define NQ 10
#define WW 113
#define BB 16
#define CC 22
#define NF 8
#define FDIM 352   // CC*NF*2
#define NS (BB*WW) // 1808
#define NGATE 23

// layout: state idx bits -> lane L[5:0] = bits {9,8,6,4,2,1}, regs r[2:0] = bits {7,5,3}, wave = bit0
// qubit q <-> bit (9-q):  L5=q0 L4=q1 r2=q2 L3=q3 r1=q4 L2=q5 r0=q6 L1=q7 L0=q8 wave=q9

__device__ __forceinline__ float2 cmulf(float2 a, float2 b) {
    return make_float2(a.x*b.x - a.y*b.y, a.x*b.y + a.y*b.x);
}
__device__ __forceinline__ void cmacf(float2& acc, float2 c, float2 v) {
    acc.x = fmaf(c.x, v.x, acc.x); acc.x = fmaf(-c.y, v.y, acc.x);
    acc.y = fmaf(c.x, v.y, acc.y); acc.y = fmaf(c.y, v.x, acc.y);
}
__device__ __forceinline__ float2 shflx(float2 v, int m) {
    return make_float2(__shfl_xor(v.x, m, 64), __shfl_xor(v.y, m, 64));
}

// ---------------- gate table (static circuit structure) -------------------
__constant__ int G_KIND[NGATE]  = {0,0,0,0,0, 0,0,0,0, 1,1,1,1,1, 0,0,0,0, 1,1, 0,0, 1};
__constant__ int G_LAYER[NGATE] = {0,0,0,0,0, 0,0,0,0, 0,0,0,0,0, 1,1,1,1, 1,1, 2,2, 2};
__constant__ int G_IA[NGATE]    = {0,2,4,6,8, 1,3,5,7, 0,1,2,3,4, 0,2,1,3, 0,1, 0,1, 0};

__device__ void u3mat(float2* U, float th, float ph, float lm) {
    float ct, st, cp, sp, cl, sl;
    sincosf(th * 0.5f, &st, &ct);
    sincosf(ph, &sp, &cp);
    sincosf(lm, &sl, &cl);
    U[0] = make_float2(ct, 0.f);
    U[1] = make_float2(-cl * st, -sl * st);
    U[2] = make_float2(cp * st, sp * st);
    U[3] = make_float2((cp * cl - sp * sl) * ct, (sp * cl + cp * sl) * ct);
}

__device__ void mm4(float2* C, const float2* A, const float2* B) {
#pragma unroll
    for (int i = 0; i < 4; ++i)
#pragma unroll
        for (int j = 0; j < 4; ++j) {
            float2 acc = make_float2(0.f, 0.f);
#pragma unroll
            for (int k = 0; k < 4; ++k) {
                float2 p = cmulf(A[i*4+k], B[k*4+j]);
                acc.x += p.x; acc.y += p.y;
            }
            C[i*4+j] = acc;
        }
}

// prep: gate matrices + softmax weights + zero out
__global__ __launch_bounds__(64) void prep_kernel(
    const float* __restrict__ conv,   // (3,10,15)
    const float* __restrict__ pool,   // (3,5,3)
    const float* __restrict__ aggw,   // (113,)
    float2* __restrict__ mats,        // (23,16)
    float* __restrict__ wts,          // (113,)
    float* __restrict__ out)          // (16,) -> zeroed
{
    const int t = threadIdx.x;

    float a0 = (t < WW) ? aggw[t] : -1e30f;
    float a1 = (t + 64 < WW) ? aggw[t + 64] : -1e30f;
    float mx = fmaxf(a0, a1);
    for (int off = 32; off > 0; off >>= 1) mx = fmaxf(mx, __shfl_xor(mx, off));
    float e0 = (t < WW) ? expf(a0 - mx) : 0.f;
    float e1 = (t + 64 < WW) ? expf(a1 - mx) : 0.f;
    float es = e0 + e1;
    for (int off = 32; off > 0; off >>= 1) es += __shfl_xor(es, off);
    float inv = 1.0f / es;
    if (t < WW) wts[t] = e0 * inv;
    if (t + 64 < WW) wts[t + 64] = e1 * inv;
    if (t < BB) out[t] = 0.f;

    if (t >= NGATE) return;
    int kind = G_KIND[t], layer = G_LAYER[t], ia = G_IA[t];
    float2 F[16];
    if (kind == 0) {
        const float* wp = conv + layer * 150;
        float2 Uw0[4], Un0[4], Uw1[4], Un1[4];
        u3mat(Uw0, wp[ia*15+0], wp[ia*15+1], wp[ia*15+2]);
        u3mat(Un0, wp[(ia+1)*15+3], wp[(ia+1)*15+4], wp[(ia+1)*15+5]);
        u3mat(Uw1, wp[ia*15+9], wp[ia*15+10], wp[ia*15+11]);
        u3mat(Un1, wp[(ia+1)*15+12], wp[(ia+1)*15+13], wp[(ia+1)*15+14]);
        float2 Kpre[16], Kpost[16];
#pragma unroll
        for (int a = 0; a < 2; ++a)
#pragma unroll
        for (int b = 0; b < 2; ++b)
#pragma unroll
        for (int c = 0; c < 2; ++c)
#pragma unroll
        for (int d = 0; d < 2; ++d) {
            Kpre [(2*a+b)*4 + (2*c+d)] = cmulf(Uw0[a*2+c], Un0[b*2+d]);
            Kpost[(2*a+b)*4 + (2*c+d)] = cmulf(Uw1[a*2+c], Un1[b*2+d]);
        }
        float cz, sz, cy, sy, cx, sx;
        sincosf(wp[ia*15+6] * 0.5f, &sz, &cz);
        sincosf(wp[ia*15+7] * 0.5f, &sy, &cy);
        sincosf(wp[ia*15+8] * 0.5f, &sx, &cx);
        float2 Z[16], Y[16], X[16];
#pragma unroll
        for (int k = 0; k < 16; ++k) { Z[k] = make_float2(0,0); Y[k] = make_float2(0,0); X[k] = make_float2(0,0); }
        Z[0]  = make_float2(cz, -sz); Z[5]  = make_float2(cz, sz);
        Z[10] = make_float2(cz,  sz); Z[15] = make_float2(cz, -sz);
        Y[0] = Y[5] = Y[10] = Y[15] = make_float2(cy, 0);
        Y[0*4+3] = make_float2(0,  sy); Y[1*4+2] = make_float2(0, -sy);
        Y[2*4+1] = make_float2(0, -sy); Y[3*4+0] = make_float2(0,  sy);
        X[0] = X[5] = X[10] = X[15] = make_float2(cx, 0);
        X[0*4+3] = X[1*4+2] = X[2*4+1] = X[3*4+0] = make_float2(0, -sx);
        float2 T1[16], M[16], T2[16];
        mm4(T1, Y, Z);
        mm4(M, X, T1);
        mm4(T2, M, Kpre);
        mm4(F, Kpost, T2);
    } else {
        const float* pp = pool + layer * 15 + ia * 3;
        float2 U[4];
        u3mat(U, pp[0], pp[1], pp[2]);
#pragma unroll
        for (int k = 0; k < 16; ++k) F[k] = make_float2(0,0);
        F[0*4+0] = make_float2(1,0); F[1*4+1] = make_float2(1,0);
        F[2*4+2] = U[0]; F[2*4+3] = U[1];
        F[3*4+2] = U[2]; F[3*4+3] = U[3];
    }
#pragma unroll
    for (int k = 0; k < 16; ++k) mats[t*16 + k] = F[k];
}

// ================== gate engines (register state, 8 amps/thread) ==========

// full 4x4 on two reg bits (RA = gate wire A pos, RB = wire B pos in reg nibble)
template<int RA, int RB>
__device__ __forceinline__ void rr_conv(float2* amp, const float2* __restrict__ m)
{
    constexpr int mask = (1<<RA) | (1<<RB);
#pragma unroll
    for (int base = 0; base < 8; ++base) {
        if (base & mask) continue;
        float2 a0 = amp[base];
        float2 a1 = amp[base | (1<<RB)];
        float2 a2 = amp[base | (1<<RA)];
        float2 a3 = amp[base | mask];
        float2 n[4];
#pragma unroll
        for (int g = 0; g < 4; ++g) {
            float2 acc = cmulf(m[g*4+0], a0);
            cmacf(acc, m[g*4+1], a1);
            cmacf(acc, m[g*4+2], a2);
            cmacf(acc, m[g*4+3], a3);
            n[g] = acc;
        }
        amp[base]           = n[0];
        amp[base | (1<<RB)] = n[1];
        amp[base | (1<<RA)] = n[2];
        amp[base | mask]    = n[3];
    }
}

// pool on two reg bits: CR = control reg pos, TR = target reg pos
template<int CR, int TR>
__device__ __forceinline__ void rr_pool(float2* amp, const float2* __restrict__ m)
{
#pragma unroll
    for (int base = 0; base < 8; ++base) {
        if (!((base >> CR) & 1)) continue;
        if ((base >> TR) & 1) continue;
        float2 a2 = amp[base], a3 = amp[base | (1<<TR)];
        float2 n2 = cmulf(m[10], a2); cmacf(n2, m[11], a3);
        float2 n3 = cmulf(m[14], a2); cmacf(n3, m[15], a3);
        amp[base] = n2; amp[base | (1<<TR)] = n3;
    }
}

template<bool RIA>
__device__ __forceinline__ constexpr int gidx(int rb, int lb) {
    return RIA ? rb*2 + lb : lb*2 + rb;
}

// full 4x4, one wire on reg pos RP, other on lane bit LPOS. RIA: reg wire is A.
template<int RP, int LPOS, bool RIA>
__device__ __forceinline__ void rl_conv(float2* amp, const float2* __restrict__ m, int L)
{
    const int vL = (L >> LPOS) & 1;
    constexpr int xm = 1 << LPOS;
    float2 pamp[8];
#pragma unroll
    for (int r = 0; r < 8; ++r) pamp[r] = shflx(amp[r], xm);
    float2 cOwn[2][2], cPar[2][2];
#pragma unroll
    for (int bo = 0; bo < 2; ++bo)
#pragma unroll
    for (int bi = 0; bi < 2; ++bi) {
        cOwn[bo][bi] = vL ? m[gidx<RIA>(bo,1)*4 + gidx<RIA>(bi,1)]
                          : m[gidx<RIA>(bo,0)*4 + gidx<RIA>(bi,0)];
        cPar[bo][bi] = vL ? m[gidx<RIA>(bo,1)*4 + gidx<RIA>(bi,0)]
                          : m[gidx<RIA>(bo,0)*4 + gidx<RIA>(bi,1)];
    }
    float2 out[8];
#pragma unroll
    for (int r = 0; r < 8; ++r) {
        constexpr int RPC = RP;  // keep r-derived indices compile-time
        const int bo = (r >> RPC) & 1;
        const int r0 = r & ~(1 << RPC), r1 = r | (1 << RPC);
        float2 acc = cmulf(bo ? cOwn[1][0] : cOwn[0][0], amp[r0]);
        cmacf(acc, bo ? cOwn[1][1] : cOwn[0][1], amp[r1]);
        cmacf(acc, bo ? cPar[1][0] : cPar[0][0], pamp[r0]);
        cmacf(acc, bo ? cPar[1][1] : cPar[0][1], pamp[r1]);
        out[r] = acc;
    }
#pragma unroll
    for (int r = 0; r < 8; ++r) amp[r] = out[r];
}

// pool with control on LANE bit LPOS, target on reg pos RP (no shfl at all)
template<int RP, int LPOS>
__device__ __forceinline__ void rl_pool_clane(float2* amp, const float2* __restrict__ m, int L)
{
    const int vC = (L >> LPOS) & 1;
    float2 out[8];
#pragma unroll
    for (int r = 0; r < 8; ++r) {
        const int bo = (r >> RP) & 1;
        const int r0 = r & ~(1 << RP), r1 = r | (1 << RP);
        float2 acc = cmulf(bo ? m[14] : m[10], amp[r0]);
        cmacf(acc, bo ? m[15] : m[11], amp[r1]);
        out[r] = vC ? acc : amp[r];
    }
#pragma unroll
    for (int r = 0; r < 8; ++r) amp[r] = out[r];
}

// pool with control on reg pos RP, target on lane bit LPOS
template<int RP, int LPOS>
__device__ __forceinline__ void rl_pool_creg(float2* amp, const float2* __restrict__ m, int L)
{
    const int vT = (L >> LPOS) & 1;
    constexpr int xm = 1 << LPOS;
    float2 cO = vT ? m[15] : m[10];
    float2 cP = vT ? m[14] : m[11];
#pragma unroll
    for (int r = 0; r < 8; ++r) {
        if (!((r >> RP) & 1)) continue;
        float2 p = shflx(amp[r], xm);
        float2 nv = cmulf(cO, amp[r]); cmacf(nv, cP, p);
        amp[r] = nv;
    }
}

// full 4x4 on two lane bits LA (wire A), LB (wire B)
template<int LA, int LB>
__device__ __forceinline__ void ll_conv(float2* amp, const float2* __restrict__ m, int L)
{
    const int vA = (L >> LA) & 1, vB = (L >> LB) & 1;
    constexpr int ma = 1 << LA, mb = 1 << LB;
#define SEL4(e0, e1, e2, e3) (vA ? (vB ? (e3) : (e2)) : (vB ? (e1) : (e0)))
    float2 cS  = SEL4(m[0],  m[5],  m[10], m[15]);
    float2 cA  = SEL4(m[2],  m[7],  m[8],  m[13]);
    float2 cB  = SEL4(m[1],  m[4],  m[11], m[14]);
    float2 cAB = SEL4(m[3],  m[6],  m[9],  m[12]);
#undef SEL4
    float2 out[8];
#pragma unroll
    for (int r = 0; r < 8; ++r) out[r] = cmulf(cS, amp[r]);
#pragma unroll
    for (int r = 0; r < 8; ++r) { float2 p = shflx(amp[r], ma); cmacf(out[r], cA, p); }
#pragma unroll
    for (int r = 0; r < 8; ++r) { float2 p = shflx(amp[r], mb); cmacf(out[r], cB, p); }
#pragma unroll
    for (int r = 0; r < 8; ++r) { float2 p = shflx(amp[r], ma^mb); cmacf(out[r], cAB, p); }
#pragma unroll
    for (int r = 0; r < 8; ++r) amp[r] = out[r];
}

// pool with control on lane CA, target on lane TB
template<int CA, int TB>
__device__ __forceinline__ void ll_pool(float2* amp, const float2* __restrict__ m, int L)
{
    const int vC = (L >> CA) & 1, vT = (L >> TB) & 1;
    constexpr int mb = 1 << TB;
    float2 cO = vT ? m[15] : m[10];
    float2 cP = vT ? m[14] : m[11];
#pragma unroll
    for (int r = 0; r < 8; ++r) {
        float2 p = shflx(amp[r], mb);
        float2 nv = cmulf(cO, amp[r]); cmacf(nv, cP, p);
        amp[r] = vC ? nv : amp[r];
    }
}

// ---------------- fused kernel --------------------------------------------
__global__ __launch_bounds__(128, 4) void fused_kernel(
    const float* __restrict__ x,           // (16,22,128)
    const float* __restrict__ proj_w,      // (10,352)
    const float* __restrict__ proj_b,      // (10,)
    const float* __restrict__ freq_scale,  // (10,)
    const float2* __restrict__ mats,       // (23,16)
    const float* __restrict__ wts,         // (113,)
    float* __restrict__ out)               // (16,)
{
    const int s = blockIdx.x;
    const int b = s / WW, w = s % WW;
    const int tid = threadIdx.x;
    const int wv  = tid >> 6;    // wave = state bit 0 (qubit 9)
    const int L   = tid & 63;

    __shared__ float2 buf[1024];          // 8 KB; overlaid feature staging
    float*  win  = (float*)buf;           // floats [0,352)
    float*  feat = (float*)buf + 384;     // floats [384,736)
    float2* tw   = buf + 400;             // float2 [400,416)
    float2* vq   = buf + 416;             // float2 [416,436)
    float*  angs = (float*)buf + 880;     // floats [880,890)

    // ---- features ----
    const float* xb = x + b * (CC * 128) + w;
    for (int e = tid; e < CC * 16; e += 128) {
        int c = e >> 4, n = e & 15;
        win[e] = xb[c * 128 + n];
    }
    if (tid < 16) {
        float ang = -(float)M_PI * (float)tid * 0.125f;
        float sv, cv; sincosf(ang, &sv, &cv);
        tw[tid] = make_float2(cv, sv);
    }
    __syncthreads();

    for (int pidx = tid; pidx < CC * NF; pidx += 128) {
        int c = pidx >> 3, k = pidx & 7;
        float re = 0.f, im = 0.f;
#pragma unroll
        for (int n = 0; n < 16; ++n) {
            int mm = (k * n) & 15;
            float2 t = tw[mm];
            float xv = win[c * 16 + n];
            re = fmaf(xv, t.x, re);
            im = fmaf(xv, t.y, im);
        }
        feat[c * 16 + (k << 1)]     = log1pf(sqrtf(re * re + im * im));
        feat[c * 16 + (k << 1) + 1] = atan2f(im, re) * (float)(1.0 / M_PI);
    }
    __syncthreads();

    // projection: wave wv handles q = wv, wv+2, ... (5 each)
    {
        float fv[6];
#pragma unroll
        for (int k = 0; k < 6; ++k) {
            int e = L + 64 * k;
            fv[k] = (e < FDIM) ? feat[e] : 0.f;
        }
        for (int q = wv; q < NQ; q += 2) {
            const float* pw = proj_w + q * FDIM + L;
            float acc = 0.f;
#pragma unroll
            for (int k = 0; k < 6; ++k) {
                float wvv = (L + 64 * k < FDIM) ? pw[64 * k] : 0.f;
                acc = fmaf(fv[k], wvv, acc);
            }
#pragma unroll
            for (int off = 32; off > 0; off >>= 1) acc += __shfl_xor(acc, off);
            if (L == 0) angs[q] = acc;
        }
    }
    __syncthreads();

    if (tid < NQ) {
        float a = tanhf(angs[tid] + proj_b[tid]) * (float)M_PI;
        float bf = freq_scale[tid] * a;
        float ca, sa, cb, sb;
        sincosf(a * 0.5f, &sa, &ca);
        sincosf(bf * 0.5f, &sb, &cb);
        vq[2 * tid]     = make_float2(cb * ca, -sb * sa);
        vq[2 * tid + 1] = make_float2(cb * sa, -sb * ca);
    }
    __syncthreads();

    // ---- init product state into 8 regs ----
    // lane bits: L5=q0 L4=q1 L3=q3 L2=q5 L1=q7 L0=q8; wave=q9; regs r2=q2 r1=q4 r0=q6
    float2 amp[8];
    {
        float2 pre = vq[2*0 + ((L>>5)&1)];
        pre = cmulf(pre, vq[2*1 + ((L>>4)&1)]);
        pre = cmulf(pre, vq[2*3 + ((L>>3)&1)]);
        pre = cmulf(pre, vq[2*5 + ((L>>2)&1)]);
        pre = cmulf(pre, vq[2*7 + ((L>>1)&1)]);
        pre = cmulf(pre, vq[2*8 + (L&1)]);
        pre = cmulf(pre, vq[2*9 + wv]);
        float2 f2[2] = { vq[2*2], vq[2*2+1] };
        float2 f4[2] = { vq[2*4], vq[2*4+1] };
        float2 f6[2] = { vq[2*6], vq[2*6+1] };
        float2 t46[4];
#pragma unroll
        for (int i = 0; i < 4; ++i) t46[i] = cmulf(f4[i>>1], f6[i&1]);
#pragma unroll
        for (int r = 0; r < 8; ++r)
            amp[r] = cmulf(cmulf(pre, f2[(r>>2)&1]), t46[r & 3]);
    }

    // ---- gates in program order ----
    ll_conv<5,4>(amp, mats + 0*16, L);            // m0  (q0,q1) bits(9,8)
    rl_conv<2,3,true >(amp, mats + 1*16, L);      // m1  (q2,q3) bits(7,6)
    rl_conv<1,2,true >(amp, mats + 2*16, L);      // m2  (q4,q5) bits(5,4)
    rl_conv<0,1,true >(amp, mats + 3*16, L);      // m3  (q6,q7) bits(3,2)
    {                                             // m4  (q8,q9) bits(1,0): lane L0 = A, wave = B
        const float2* m = mats + 4*16;
        __syncthreads();   // vq reads done; claim buf
#pragma unroll
        for (int r = 0; r < 8; ++r) buf[wv*512 + r*64 + L] = amp[r];
        __syncthreads();
        const int vA = L & 1;
        float2 cS, cL, cW, cLW;
        if (wv == 0) {
            cS  = vA ? m[10] : m[0];
            cL  = vA ? m[8]  : m[2];
            cW  = vA ? m[11] : m[1];
            cLW = vA ? m[9]  : m[3];
        } else {
            cS  = vA ? m[15] : m[5];
            cL  = vA ? m[13] : m[7];
            cW  = vA ? m[14] : m[4];
            cLW = vA ? m[12] : m[6];
        }
        float2 o[8];
#pragma unroll
        for (int r = 0; r < 8; ++r) {
            float2 oW  = buf[(wv^1)*512 + r*64 + L];
            float2 oWL = buf[(wv^1)*512 + r*64 + (L^1)];
            float2 oL  = shflx(amp[r], 1);
            float2 acc = cmulf(cS, amp[r]);
            cmacf(acc, cL, oL);
            cmacf(acc, cW, oW);
            cmacf(acc, cLW, oWL);
            o[r] = acc;
        }
#pragma unroll
        for (int r = 0; r < 8; ++r) amp[r] = o[r];
    }
    rl_conv<2,4,false>(amp, mats + 5*16, L);      // m5  (q1,q2) bits(8,7)
    rl_conv<1,3,false>(amp, mats + 6*16, L);      // m6  (q3,q4) bits(6,5)
    rl_conv<0,2,false>(amp, mats + 7*16, L);      // m7  (q5,q6) bits(4,3)
    ll_conv<1,0>(amp, mats + 8*16, L);            // m8  (q7,q8) bits(2,1)
    ll_pool<4,5>(amp, mats + 9*16, L);            // m9  ctrl q1(bit8=L4) -> tgt q0(bit9=L5)
    rl_pool_clane<2,3>(amp, mats + 10*16, L);     // m10 ctrl q3(L3) -> tgt q2(r2)
    rl_pool_clane<1,2>(amp, mats + 11*16, L);     // m11 ctrl q5(L2) -> tgt q4(r1)
    rl_pool_clane<0,1>(amp, mats + 12*16, L);     // m12 ctrl q7(L1) -> tgt q6(r0)
    if (wv == 1) {                                // m13 ctrl q9(wave) -> tgt q8(L0)
        const float2* m = mats + 13*16;
        const int vB = L & 1;
        float2 cO = vB ? m[15] : m[10];
        float2 cP = vB ? m[14] : m[11];
#pragma unroll
        for (int r = 0; r < 8; ++r) {
            float2 p = shflx(amp[r], 1);
            float2 nv = cmulf(cO, amp[r]); cmacf(nv, cP, p);
            amp[r] = nv;
        }
    }
    rl_conv<2,5,false>(amp, mats + 14*16, L);     // m14 (q0,q2) bits(9,7)
    rr_conv<1,0>(amp, mats + 15*16);              // m15 (q4,q6) bits(5,3)
    rr_conv<2,1>(amp, mats + 16*16);              // m16 (q2,q4) bits(7,5)
    rl_conv<0,0,true >(amp, mats + 17*16, L);     // m17 (q6,q8) bits(3,1)
    rl_pool_creg<2,5>(amp, mats + 18*16, L);      // m18 ctrl q2(r2) -> tgt q0(L5)
    rr_pool<0,1>(amp, mats + 19*16);              // m19 ctrl q6(r0) -> tgt q4(r1)
    rl_conv<1,5,false>(amp, mats + 20*16, L);     // m20 (q0,q4) bits(9,5)
    rl_conv<1,0,true >(amp, mats + 21*16, L);     // m21 (q4,q8) bits(5,1)
    rl_pool_creg<1,5>(amp, mats + 22*16, L);      // m22 ctrl q4(r1) -> tgt q0(L5)

    // ---- measurement: qubit 0 = bit9 = L5 ----
    float local = 0.f;
#pragma unroll
    for (int r = 0; r < 8; ++r)
        local += amp[r].x * amp[r].x + amp[r].y * amp[r].y;
    local = ((L >> 5) & 1) ? -local : local;
#pragma unroll
    for (int off = 32; off > 0; off >>= 1) local += __shfl_xor(local, off);
    if (L == 0) atomicAdd(&out[b], local * wts[w]);
}

extern "C" void kernel_launch(void* const* d_in, const int* in_sizes, int n_in,
                              void* d_out, int out_size, void* d_ws, size_t ws_size,
                              hipStream_t stream)
{
    const float* x           = (const float*)d_in[0];
    const float* proj_w      = (const float*)d_in[1];
    const float* proj_b      = (const float*)d_in[2];
    const float* freq_scale  = (const float*)d_in[3];
    const float* conv_params = (const float*)d_in[4];
    const float* pool_params = (const float*)d_in[5];
    const float* aggw        = (const float*)d_in[6];
    float* out = (float*)d_out;

    float2* mats = (float2*)d_ws;                 // 23*16 float2
    float* wts   = (float*)d_ws + NGATE * 16 * 2; // 113 floats

    prep_kernel<<<1, 64, 0, stream>>>(conv_params, pool_params, aggw, mats, wts, out);
    fused_kernel<<<NS, 128, 0, stream>>>(x, proj_w, proj_b, freq_scale, mats, wts, out);
}

// Round 7
// 116.164 us; speedup vs baseline: 1.1782x; 1.1782x over previous
//
#include <hip/hip_runtime.h>
#include <math.h>

#define NQ 10
#define WW 113
#define BB 16
#define CC 22
#define NF 8
#define FDIM 352   // CC*NF*2
#define NS (BB*WW) // 1808
#define NGATE 23

__device__ __forceinline__ constexpr int SLOT(int j) { return j ^ ((j >> 5) & 31); }

__device__ __forceinline__ float2 cmulf(float2 a, float2 b) {
    return make_float2(a.x*b.x - a.y*b.y, a.x*b.y + a.y*b.x);
}
__device__ __forceinline__ void cmacf(float2& acc, float2 c, float2 v) {
    acc.x = fmaf(c.x, v.x, acc.x); acc.x = fmaf(-c.y, v.y, acc.x);
    acc.y = fmaf(c.x, v.y, acc.y); acc.y = fmaf(c.y, v.x, acc.y);
}

// ---------------- gate table (static circuit structure) -------------------
__constant__ int G_KIND[NGATE]  = {0,0,0,0,0, 0,0,0,0, 1,1,1,1,1, 0,0,0,0, 1,1, 0,0, 1};
__constant__ int G_LAYER[NGATE] = {0,0,0,0,0, 0,0,0,0, 0,0,0,0,0, 1,1,1,1, 1,1, 2,2, 2};
__constant__ int G_IA[NGATE]    = {0,2,4,6,8, 1,3,5,7, 0,1,2,3,4, 0,2,1,3, 0,1, 0,1, 0};

__device__ __forceinline__ void u3mat(float2* U, float th, float ph, float lm) {
    float ct, st, cp, sp, cl, sl;
    sincosf(th * 0.5f, &st, &ct);
    sincosf(ph, &sp, &cp);
    sincosf(lm, &sl, &cl);
    U[0] = make_float2(ct, 0.f);
    U[1] = make_float2(-cl * st, -sl * st);
    U[2] = make_float2(cp * st, sp * st);
    U[3] = make_float2((cp * cl - sp * sl) * ct, (sp * cl + cp * sl) * ct);
}

// prep: one thread per matrix ELEMENT (23 gates x 16 elems = 368 threads)
__global__ __launch_bounds__(384) void prep_kernel(
    const float* __restrict__ conv,   // (3,10,15)
    const float* __restrict__ pool,   // (3,5,3)
    const float* __restrict__ aggw,   // (113,)
    float2* __restrict__ mats,        // (23,16)
    float* __restrict__ wts,          // (113,)
    float* __restrict__ out)          // (16,) -> zeroed
{
    const int t = threadIdx.x;

    if (t < 64) {  // wave 0: softmax over aggw
        float a0 = (t < WW) ? aggw[t] : -1e30f;
        float a1 = (t + 64 < WW) ? aggw[t + 64] : -1e30f;
        float mx = fmaxf(a0, a1);
        for (int off = 32; off > 0; off >>= 1) mx = fmaxf(mx, __shfl_xor(mx, off));
        float e0 = (t < WW) ? expf(a0 - mx) : 0.f;
        float e1 = (t + 64 < WW) ? expf(a1 - mx) : 0.f;
        float es = e0 + e1;
        for (int off = 32; off > 0; off >>= 1) es += __shfl_xor(es, off);
        float inv = 1.0f / es;
        if (t < WW) wts[t] = e0 * inv;
        if (t + 64 < WW) wts[t + 64] = e1 * inv;
        if (t < BB) out[t] = 0.f;
    }

    if (t >= NGATE * 16) return;
    const int g = t >> 4, k = t & 15;
    const int i = k >> 2, j = k & 3;
    const int kind = G_KIND[g], layer = G_LAYER[g], ia = G_IA[g];
    float2 F;
    if (kind == 1) {
        const float* pp = pool + layer * 15 + ia * 3;
        if (i < 2 || j < 2) {
            F = (i == j) ? make_float2(1.f, 0.f) : make_float2(0.f, 0.f);
        } else {
            float2 U[4];
            u3mat(U, pp[0], pp[1], pp[2]);
            F = U[(i - 2) * 2 + (j - 2)];
        }
    } else {
        const float* wp = conv + layer * 150;
        float2 Uw0[4], Un0[4], Uw1[4], Un1[4];
        u3mat(Uw0, wp[ia*15+0],  wp[ia*15+1],  wp[ia*15+2]);
        u3mat(Un0, wp[(ia+1)*15+3],  wp[(ia+1)*15+4],  wp[(ia+1)*15+5]);
        u3mat(Uw1, wp[ia*15+9],  wp[ia*15+10], wp[ia*15+11]);
        u3mat(Un1, wp[(ia+1)*15+12], wp[(ia+1)*15+13], wp[(ia+1)*15+14]);
        float cz, sz, cy, sy, cx, sx;
        sincosf(wp[ia*15+6] * 0.5f, &sz, &cz);
        sincosf(wp[ia*15+7] * 0.5f, &sy, &cy);
        sincosf(wp[ia*15+8] * 0.5f, &sx, &cx);
        // M = X*Y*Z nonzero only at (a,a) and (a,3-a); z_{3-a}==z_a
        float2 acc = make_float2(0.f, 0.f);
#pragma unroll
        for (int a = 0; a < 4; ++a) {
            const float sa = (a == 0 || a == 3) ? 1.f : -1.f;
            const float2 za = (a == 0 || a == 3) ? make_float2(cz, -sz)
                                                 : make_float2(cz,  sz);
            const float daa = fmaf(sa * sx, sy, cx * cy);
            const float oaa = fmaf(sa * sy, cx, -sx * cy);
            float2 Mdiag = make_float2(daa * za.x, daa * za.y);
            float2 Moff  = make_float2(-oaa * za.y, oaa * za.x);
            float2 kpost = cmulf(Uw1[(i >> 1) * 2 + (a >> 1)], Un1[(i & 1) * 2 + (a & 1)]);
            float2 kpreA = cmulf(Uw0[(a >> 1) * 2 + (j >> 1)], Un0[(a & 1) * 2 + (j & 1)]);
            float2 kpreN = cmulf(Uw0[(1 - (a >> 1)) * 2 + (j >> 1)], Un0[(1 - (a & 1)) * 2 + (j & 1)]);
            float2 inner = cmulf(Mdiag, kpreA);
            cmacf(inner, Moff, kpreN);
            cmacf(acc, kpost, inner);
        }
        F = acc;
    }
    mats[g * 16 + k] = F;
}

// ================== register-state engine (16 amps/thread, 1 wave/sample) ==

template<int B3,int B2,int B1,int B0>
__device__ __forceinline__ int lanepart(int L) {
    constexpr int rm = (1<<B3)|(1<<B2)|(1<<B1)|(1<<B0);
    int idx = 0, lb = 5;
#pragma unroll
    for (int p = 9; p >= 0; --p)
        if (!((rm >> p) & 1)) { idx |= ((L >> lb) & 1) << p; --lb; }
    return idx;
}

template<int B3,int B2,int B1,int B0>
__device__ __forceinline__ int rpart(int r) {
    return (((r>>3)&1)<<B3) | (((r>>2)&1)<<B2) | (((r>>1)&1)<<B1) | ((r&1)<<B0);
}

// full 4x4 gate on register-nibble positions PA (wire A), PB (wire B)
template<int PA, int PB>
__device__ __forceinline__ void rgate(float2* amp, const float2* __restrict__ m)
{
    constexpr int mask = (1<<PA) | (1<<PB);
#pragma unroll
    for (int base = 0; base < 16; ++base) {
        if (base & mask) continue;
        float2 a0 = amp[base];
        float2 a1 = amp[base | (1<<PB)];
        float2 a2 = amp[base | (1<<PA)];
        float2 a3 = amp[base | mask];
        float2 n[4];
#pragma unroll
        for (int g = 0; g < 4; ++g) {
            float2 acc = cmulf(m[g*4+0], a0);
            cmacf(acc, m[g*4+1], a1);
            cmacf(acc, m[g*4+2], a2);
            cmacf(acc, m[g*4+3], a3);
            n[g] = acc;
        }
        amp[base]           = n[0];
        amp[base | (1<<PB)] = n[1];
        amp[base | (1<<PA)] = n[2];
        amp[base | mask]    = n[3];
    }
}

// cu3 pool: control at nibble pos CR, target at pos TR (2-term)
template<int CR, int TR>
__device__ __forceinline__ void rr_pool(float2* amp, const float2* __restrict__ m)
{
#pragma unroll
    for (int r = 0; r < 16; ++r) {
        if (!((r >> CR) & 1) || ((r >> TR) & 1)) continue;
        float2 a2 = amp[r], a3 = amp[r | (1<<TR)];
        float2 n2 = cmulf(m[10], a2); cmacf(n2, m[11], a3);
        float2 n3 = cmulf(m[14], a2); cmacf(n3, m[15], a3);
        amp[r] = n2; amp[r | (1<<TR)] = n3;
    }
}

// re-layout between register-bit partitions through this wave's LDS region.
// Single wave: LDS ops are in-order within a wave -> no fences needed.
template<int O3,int O2,int O1,int O0, int N3,int N2,int N1,int N0>
__device__ __forceinline__ void relayout(float2* wst, float2* amp, int L)
{
    const int lo = lanepart<O3,O2,O1,O0>(L);
#pragma unroll
    for (int r = 0; r < 16; ++r) {
        const int idx = lo | rpart<O3,O2,O1,O0>(r);
        wst[SLOT(idx)] = amp[r];
    }
    const int ln = lanepart<N3,N2,N1,N0>(L);
#pragma unroll
    for (int r = 0; r < 16; ++r) {
        const int idx = ln | rpart<N3,N2,N1,N0>(r);
        amp[r] = wst[SLOT(idx)];
    }
}

// ---------------- fused kernel: 1 wave per sample --------------------------
__global__ __launch_bounds__(64) void fused_kernel(
    const float* __restrict__ x,           // (16,22,128)
    const float* __restrict__ proj_w,      // (10,352)
    const float* __restrict__ proj_b,      // (10,)
    const float* __restrict__ freq_scale,  // (10,)
    const float2* __restrict__ mats,       // (23,16)
    const float* __restrict__ wts,         // (113,)
    float* __restrict__ out)               // (16,)
{
    const int s = blockIdx.x;
    const int b = s / WW, w = s % WW;
    const int L = threadIdx.x;   // 0..63, single wave

    __shared__ float2 wst[1024];          // 8 KB; overlaid feature staging
    float*  win  = (float*)wst;           // floats [0,352)
    float*  feat = (float*)wst + 384;     // floats [384,736)
    float2* tw   = wst + 400;             // float2 [400,416)
    float2* vq   = wst + 416;             // float2 [416,436)
    float*  angs = (float*)wst + 880;     // floats [880,890)

    // ---- features (wave-synchronous; no barriers) ----
    const float* xb = x + b * (CC * 128) + w;
#pragma unroll
    for (int kk = 0; kk < 6; ++kk) {
        int e = L + 64 * kk;
        if (e < CC * 16) {
            int c = e >> 4, n = e & 15;
            win[e] = xb[c * 128 + n];
        }
    }
    if (L < 16) {
        float ang = -(float)M_PI * (float)L * 0.125f;
        float sv, cv; sincosf(ang, &sv, &cv);
        tw[L] = make_float2(cv, sv);
    }

    for (int pidx = L; pidx < CC * NF; pidx += 64) {
        int c = pidx >> 3, k = pidx & 7;
        float re = 0.f, im = 0.f;
#pragma unroll
        for (int n = 0; n < 16; ++n) {
            int mm = (k * n) & 15;
            float2 t = tw[mm];
            float xv = win[c * 16 + n];
            re = fmaf(xv, t.x, re);
            im = fmaf(xv, t.y, im);
        }
        feat[c * 16 + (k << 1)]     = log1pf(sqrtf(re * re + im * im));
        feat[c * 16 + (k << 1) + 1] = atan2f(im, re) * (float)(1.0 / M_PI);
    }

    // projection: 10 dots of length 352
    {
        float fv[6];
#pragma unroll
        for (int k = 0; k < 6; ++k) {
            int e = L + 64 * k;
            fv[k] = (e < FDIM) ? feat[e] : 0.f;
        }
        for (int q = 0; q < NQ; ++q) {
            const float* pw = proj_w + q * FDIM + L;
            float acc = 0.f;
#pragma unroll
            for (int k = 0; k < 6; ++k) {
                float wv = (L + 64 * k < FDIM) ? pw[64 * k] : 0.f;
                acc = fmaf(fv[k], wv, acc);
            }
#pragma unroll
            for (int off = 32; off > 0; off >>= 1) acc += __shfl_xor(acc, off);
            if (L == 0) angs[q] = acc;
        }
    }

    if (L < NQ) {
        float a = tanhf(angs[L] + proj_b[L]) * (float)M_PI;
        float bf = freq_scale[L] * a;
        float ca, sa, cb, sb;
        sincosf(a * 0.5f, &sa, &ca);
        sincosf(bf * 0.5f, &sb, &cb);
        vq[2 * L]     = make_float2(cb * ca, -sb * sa);
        vq[2 * L + 1] = make_float2(cb * sa, -sb * ca);
    }

    // ---- init in partition A {9,8,7,6}: lane = idx[5:0], r = idx[9:6] ----
    float2 amp[16];
    {
        float2 pre = make_float2(1.f, 0.f);
#pragma unroll
        for (int p = 0; p < 6; ++p) {
            float2 f = vq[2 * (9 - p) + ((L >> p) & 1)];
            pre = cmulf(pre, f);
        }
        float2 p98[4], p76[4];
#pragma unroll
        for (int i = 0; i < 4; ++i) {
            p98[i] = cmulf(vq[2 * 0 + (i >> 1)], vq[2 * 1 + (i & 1)]); // bits 9,8
            p76[i] = cmulf(vq[2 * 2 + (i >> 1)], vq[2 * 3 + (i & 1)]); // bits 7,6
        }
#pragma unroll
        for (int r = 0; r < 16; ++r)
            amp[r] = cmulf(pre, cmulf(p98[r >> 2], p76[r & 3]));
    }

    // ---- 6 rounds of register gates + 5 relayouts (schedule verified r4) ----
    // A {9,8,7,6}
    rgate<3,2>(amp, mats + 0*16);      // m0 (q0,q1)
    rgate<1,0>(amp, mats + 1*16);      // m1 (q2,q3)
    rgate<2,1>(amp, mats + 5*16);      // m5 (q1,q2)
    rr_pool<2,3>(amp, mats + 9*16);    // m9 ctrl q1 -> q0
    relayout<9,8,7,6, 5,4,3,2>(wst, amp, L);
    // B {5,4,3,2}
    rgate<3,2>(amp, mats + 2*16);      // m2 (q4,q5)
    rgate<1,0>(amp, mats + 3*16);      // m3 (q6,q7)
    rgate<2,1>(amp, mats + 7*16);      // m7 (q5,q6)
    relayout<5,4,3,2, 7,6,5,4>(wst, amp, L);
    // C1 {7,6,5,4}
    rgate<2,1>(amp, mats + 6*16);      // m6 (q3,q4)
    rr_pool<2,3>(amp, mats + 10*16);   // m10 ctrl q3 -> q2
    rr_pool<0,1>(amp, mats + 11*16);   // m11 ctrl q5 -> q4
    relayout<7,6,5,4, 3,2,1,0>(wst, amp, L);
    // C2 {3,2,1,0}
    rgate<1,0>(amp, mats + 4*16);      // m4 (q8,q9)
    rgate<2,1>(amp, mats + 8*16);      // m8 (q7,q8)
    rr_pool<2,3>(amp, mats + 12*16);   // m12 ctrl q7 -> q6
    rr_pool<0,1>(amp, mats + 13*16);   // m13 ctrl q9 -> q8
    relayout<3,2,1,0, 9,7,5,3>(wst, amp, L);
    // D0 {9,7,5,3}
    rgate<3,2>(amp, mats + 14*16);     // m14 (q0,q2)
    rgate<1,0>(amp, mats + 15*16);     // m15 (q4,q6)
    rgate<2,1>(amp, mats + 16*16);     // m16 (q2,q4)
    rr_pool<2,3>(amp, mats + 18*16);   // m18 ctrl q2 -> q0
    relayout<9,7,5,3, 9,5,3,1>(wst, amp, L);
    // D1 {9,5,3,1}
    rgate<1,0>(amp, mats + 17*16);     // m17 (q6,q8)
    rr_pool<1,2>(amp, mats + 19*16);   // m19 ctrl q6 -> q4
    rgate<3,2>(amp, mats + 20*16);     // m20 (q0,q4)
    rgate<2,0>(amp, mats + 21*16);     // m21 (q4,q8)
    rr_pool<2,3>(amp, mats + 22*16);   // m22 ctrl q4 -> q0

    // ---- measurement: state bit 9 (qubit 0) = register-nibble bit 3 ----
    float local = 0.f;
#pragma unroll
    for (int r = 0; r < 16; ++r) {
        float p = amp[r].x * amp[r].x + amp[r].y * amp[r].y;
        local += (r & 8) ? -p : p;
    }
#pragma unroll
    for (int off = 32; off > 0; off >>= 1) local += __shfl_xor(local, off);
    if (L == 0) atomicAdd(&out[b], local * wts[w]);
}

extern "C" void kernel_launch(void* const* d_in, const int* in_sizes, int n_in,
                              void* d_out, int out_size, void* d_ws, size_t ws_size,
                              hipStream_t stream)
{
    const float* x           = (const float*)d_in[0];
    const float* proj_w      = (const float*)d_in[1];
    const float* proj_b      = (const float*)d_in[2];
    const float* freq_scale  = (const float*)d_in[3];
    const float* conv_params = (const float*)d_in[4];
    const float* pool_params = (const float*)d_in[5];
    const float* aggw        = (const float*)d_in[6];
    float* out = (float*)d_out;

    float2* mats = (float2*)d_ws;                 // 23*16 float2
    float* wts   = (float*)d_ws + NGATE * 16 * 2; // 113 floats

    prep_kernel<<<1, 384, 0, stream>>>(conv_params, pool_params, aggw, mats, wts, out);
    fused_kernel<<<NS, 64, 0, stream>>>(x, proj_w, proj_b, freq_scale, mats, wts, out);
}